// Round 9
// baseline (174.950 us; speedup 1.0000x reference)
//
#include <hip/hip_runtime.h>
#include <hip/hip_fp16.h>
#include <math.h>

#define N_PTS   8192
#define ENC     384
#define NTHREAD 384
#define NCELL1  8
#define NCELLS  512
#define RADIUS  0.12f

typedef _Float16 f16x8 __attribute__((ext_vector_type(8)));
typedef float    f32x4 __attribute__((ext_vector_type(4)));

__device__ __forceinline__ void fast_sincos(float x, float& s, float& c) {
    // gfx950 v_sin/v_cos take REVOLUTIONS. rev err <= |x|*2^-24 — negligible here.
    float rev = x * 0.15915494309189535f;
    rev -= rintf(rev);
    s = __builtin_amdgcn_sinf(rev);
    c = __builtin_amdgcn_cosf(rev);
}

__device__ __forceinline__ int cell_of(float x) {
    int c = (int)(x * 8.0f);
    return min(NCELL1 - 1, max(0, c));
}

// ---------------- ws layout (bytes) ----------------
static const size_t OFF_CSTART_I = 0;                      // 520 ints (513 used)
static const size_t OFF_SPTS_B   = 520 * 4;                // 2080 (16B aligned)
static const size_t OFF_CST_B    = OFF_SPTS_B + (size_t)N_PTS * 16;   // 133152
// csT: [768][8192] f16, SORTED point order. row d<384 = cos_d, row 384+d = sin_d.
static const size_t WS_FULL_B    = OFF_CST_B + (size_t)2 * ENC * N_PTS * 2 + 1024; // ~12.72MB

// ---------------- K1: count + scan + scatter, one block (proven R7/R8) ----------------
__global__ __launch_bounds__(1024) void k_prep(const float* __restrict__ pts,
                                               int* __restrict__ cell_start_g,
                                               float4* __restrict__ spts) {
    __shared__ int cnt[NCELLS];
    __shared__ int sc[NCELLS];
    __shared__ int cur[NCELLS];
    const int t = threadIdx.x;
    if (t < NCELLS) cnt[t] = 0;
    __syncthreads();

    int   cids[8];
    float xs[8], ys[8], zs[8];
    #pragma unroll
    for (int k = 0; k < 8; ++k) {
        int i = t + k * 1024;
        float x = pts[3 * i + 0], y = pts[3 * i + 1], z = pts[3 * i + 2];
        xs[k] = x; ys[k] = y; zs[k] = z;
        int cid = (cell_of(x) << 6) | (cell_of(y) << 3) | cell_of(z);
        cids[k] = cid;
        atomicAdd(&cnt[cid], 1);
    }
    __syncthreads();
    if (t < NCELLS) sc[t] = cnt[t];
    __syncthreads();
    for (int off = 1; off < NCELLS; off <<= 1) {
        int v = 0;
        if (t < NCELLS && t >= off) v = sc[t - off];
        __syncthreads();
        if (t < NCELLS) sc[t] += v;
        __syncthreads();
    }
    if (t < NCELLS) {
        int excl = sc[t] - cnt[t];
        cell_start_g[t] = excl;
        cur[t] = excl;
    }
    if (t == 0) cell_start_g[NCELLS] = N_PTS;
    __syncthreads();
    #pragma unroll
    for (int k = 0; k < 8; ++k) {
        int i = t + k * 1024;
        int pos = atomicAdd(&cur[cids[k]], 1);
        spts[pos] = make_float4(xs[k], ys[k], zs[k], __int_as_float(i));
    }
}

// ---------------- K2: csT[d][j]=cos, csT[384+d][j]=sin (f16, sorted order) ----------------
__global__ __launch_bounds__(NTHREAD) void k_encode(const float4* __restrict__ spts,
                                                    const float* __restrict__ A,
                                                    unsigned short* __restrict__ csT) {
    const int d = blockIdx.x;          // 0..383
    const int t = threadIdx.x;
    const float a0 = A[d], a1 = A[ENC + d], a2 = A[2 * ENC + d];
    for (int j = t; j < N_PTS; j += NTHREAD) {
        float4 P = spts[j];
        float qx = __fdiv_rn(P.x, RADIUS);
        float qy = __fdiv_rn(P.y, RADIUS);
        float qz = __fdiv_rn(P.z, RADIUS);
        float pa = fmaf(qz, a2, fmaf(qy, a1, qx * a0));
        float s, c;
        fast_sincos(pa, s, c);
        csT[(size_t)d * N_PTS + j]          = __half_as_ushort(__float2half_rn(c));
        csT[(size_t)(ENC + d) * N_PTS + j]  = __half_as_ushort(__float2half_rn(s));
    }
}

// ---------------- K3: per-cell masked GEMM, barrier-free stage pipeline ----------------
// grid = 1024: cell c = b&511 (x-slab swizzled per XCD), tile-slot = b>>9.
// Wave wg owns dims [64wg, 64wg+64); lane computes its own A-fragment in registers
// (8 pair tests), so NO LDS mask and NO barriers in the stage loop.
__global__ __launch_bounds__(NTHREAD, 4) void k_main(const float4* __restrict__ spts,
                                                     const int* __restrict__ cell_start,
                                                     const unsigned short* __restrict__ csT,
                                                     const float* __restrict__ A,
                                                     float* __restrict__ out, int out_mode) {
    const int b    = blockIdx.x;
    const int c    = b & 511;
    const int tl   = b >> 9;
    const int cell = (c & 7) * 64 + (c >> 3);     // XCD x-slab swizzle
    const int t    = threadIdx.x;
    const int lane = t & 63;
    const int wg   = t >> 6;       // 0..5 dim group
    const int l15  = lane & 15;
    const int kq   = lane >> 4;    // 0..3

    __shared__ float normw[6][16];
    __shared__ float scale_l[16];

    const int o_lo = cell_start[cell];
    const int o_hi = cell_start[cell + 1];
    if (o_hi <= o_lo) return;

    const int cx = cell >> 6, cy = (cell >> 3) & 7, cz = cell & 7;
    const int zlo = max(cz - 1, 0), zhi = min(cz + 1, 7);

    const double R2 = (double)0.12 * (double)0.12;
    const float R2_LO = 0.0144f - 1e-6f;
    const float R2_HI = 0.0144f + 1e-6f;

    for (int it = tl;; it += 2) {
        const int tstart = o_lo + (it << 4);
        if (tstart >= o_hi) break;

        // own point for this lane's A-row (l15); sentinel pushes d2 -> inf
        const int oid = tstart + l15;
        const float4 Pi = (oid < o_hi) ? spts[oid] : make_float4(1e9f, 1e9f, 1e9f, 0.f);

        f32x4 z; z[0] = 0.f; z[1] = 0.f; z[2] = 0.f; z[3] = 0.f;
        f32x4 aC[4] = {z, z, z, z}, aS[4] = {z, z, z, z};

        for (int r = 0; r < 9; ++r) {
            const int cxx = cx + r / 3 - 1;
            const int cyy = cy + r % 3 - 1;
            if (cxx < 0 || cxx > 7 || cyy < 0 || cyy > 7) continue;
            const int basec = (cxx * 8 + cyy) * 8;
            const int lo = cell_start[basec + zlo];      // L1 broadcast
            const int hi = cell_start[basec + zhi + 1];
            for (int jA = lo & ~7; jA < hi; jA += 32) {
                // ---- A-fragment in registers: lane tests its 8 candidates ----
                f16x8 af;
                #pragma unroll
                for (int e = 0; e < 8; ++e) {
                    const int j  = jA + kq * 8 + e;
                    const int jc = min(j, N_PTS - 1);
                    float4 Pj = spts[jc];                // 4 distinct addrs/instr: L1
                    float fdx = Pj.x - Pi.x, fdy = Pj.y - Pi.y, fdz = Pj.z - Pi.z;
                    float d2f = fmaf(fdx, fdx, fmaf(fdy, fdy, fdz * fdz));
                    bool isnb = false;
                    if (j >= lo && j < hi) {
                        if (d2f < R2_LO) {
                            isnb = true;
                        } else if (d2f <= R2_HI) {
                            double ddx = (double)Pj.x - (double)Pi.x;
                            double ddy = (double)Pj.y - (double)Pi.y;
                            double ddz = (double)Pj.z - (double)Pi.z;
                            isnb = (ddx * ddx + ddy * ddy + ddz * ddz) < R2;
                        }
                    }
                    af[e] = isnb ? (_Float16)1.0f : (_Float16)0.0f;
                }
                // ---- B slabs + MFMA (layouts verified by R8 pass) ----
                const unsigned short* bp = csT + jA + kq * 8;
                #pragma unroll
                for (int e2 = 0; e2 < 4; ++e2) {
                    const int d = wg * 64 + e2 * 16 + l15;
                    f16x8 bc = *(const f16x8*)(bp + (size_t)d * N_PTS);
                    f16x8 bs = *(const f16x8*)(bp + (size_t)(ENC + d) * N_PTS);
                    aC[e2] = __builtin_amdgcn_mfma_f32_16x16x32_f16(af, bc, aC[e2], 0, 0, 0);
                    aS[e2] = __builtin_amdgcn_mfma_f32_16x16x32_f16(af, bs, aS[e2], 0, 0, 0);
                }
            }
        }

        // ---- epilogue: norm (phase-invariant) -> rotate -> scale -> store ----
        __syncthreads();                 // protect normw/scale_l across tile iters
        float np[4];
        #pragma unroll
        for (int reg = 0; reg < 4; ++reg) {
            float v = 0.f;
            #pragma unroll
            for (int e2 = 0; e2 < 4; ++e2)
                v += aC[e2][reg] * aC[e2][reg] + aS[e2][reg] * aS[e2][reg];
            #pragma unroll
            for (int w = 1; w <= 8; w <<= 1) v += __shfl_xor(v, w);
            np[reg] = v;
        }
        if (l15 == 0) {
            #pragma unroll
            for (int reg = 0; reg < 4; ++reg) normw[wg][kq * 4 + reg] = np[reg];
        }
        __syncthreads();
        if (t < 16) {
            float tot = normw[0][t] + normw[1][t] + normw[2][t]
                      + normw[3][t] + normw[4][t] + normw[5][t];
            scale_l[t] = sqrtf(384.0f / tot);
        }
        __syncthreads();
        #pragma unroll
        for (int e2 = 0; e2 < 4; ++e2) {
            const int d = wg * 64 + e2 * 16 + l15;
            const float a0 = A[d], a1 = A[ENC + d], a2 = A[2 * ENC + d];
            #pragma unroll
            for (int reg = 0; reg < 4; ++reg) {
                const int i = kq * 4 + reg;      // C/D row = (lane>>4)*4 + reg [m89, R8]
                if (tstart + i < o_hi) {
                    float4 Po = spts[tstart + i];          // L1 broadcast
                    int o = __float_as_int(Po.w);
                    float qx = __fdiv_rn(Po.x, RADIUS);
                    float qy = __fdiv_rn(Po.y, RADIUS);
                    float qz = __fdiv_rn(Po.z, RADIUS);
                    float pa = fmaf(qz, a2, fmaf(qy, a1, qx * a0));
                    float sv, cv;
                    fast_sincos(pa, sv, cv);
                    float Gr = aC[e2][reg], Gi = aS[e2][reg];
                    float sc = scale_l[i];
                    float re = (Gr * cv + Gi * sv) * sc;
                    float im = (Gi * cv - Gr * sv) * sc;
                    if (out_mode == 0) {
                        out[(size_t)o * ENC + d] = re;
                    } else {
                        reinterpret_cast<float2*>(out)[(size_t)o * ENC + d] =
                            make_float2(re, im);
                    }
                }
            }
        }
    }
}

// ---------------- last-resort all-pairs (ws too small; effectively dead) ----------------
__global__ __launch_bounds__(NTHREAD) void vecKM_allpairs(const float* __restrict__ pts,
                                                          const float* __restrict__ A,
                                                          float* __restrict__ out, int out_mode) {
    const int i = blockIdx.x;
    const int t = threadIdx.x;
    __shared__ float nb_x[512], nb_y[512], nb_z[512];
    __shared__ int nb_cnt;
    __shared__ float red[8];
    if (t == 0) nb_cnt = 0;
    __syncthreads();
    const float xi = pts[3 * i + 0], yi = pts[3 * i + 1], zi = pts[3 * i + 2];
    const double dxi = xi, dyi = yi, dzi = zi;
    const double R2 = (double)0.12 * (double)0.12;
    const float R2_LO = 0.0144f - 1e-6f, R2_HI = 0.0144f + 1e-6f;
    const int lane = t & 63;
    for (int jb = 0; jb < N_PTS; jb += NTHREAD) {
        const int j = jb + t;
        bool isnb = false;
        float xj = 0.f, yj = 0.f, zj = 0.f;
        if (j < N_PTS) {
            xj = pts[3 * j + 0]; yj = pts[3 * j + 1]; zj = pts[3 * j + 2];
            float fdx = xj - xi, fdy = yj - yi, fdz = zj - zi;
            float d2f = fmaf(fdx, fdx, fmaf(fdy, fdy, fdz * fdz));
            if (d2f < R2_LO) isnb = true;
            else if (d2f <= R2_HI) {
                double dx = (double)xj - dxi, dy = (double)yj - dyi, dz = (double)zj - dzi;
                isnb = (dx * dx + dy * dy + dz * dz) < R2;
            }
        }
        unsigned long long mask = __ballot(isnb);
        if (mask) {
            int leader = __ffsll((long long)mask) - 1;
            int basep = 0;
            if (lane == leader) basep = atomicAdd(&nb_cnt, __popcll(mask));
            basep = __shfl(basep, leader);
            if (isnb) {
                int pos = basep + __popcll(mask & ((1ull << lane) - 1ull));
                if (pos < 512) {
                    nb_x[pos] = (xj - xi) * (1.0f / 0.12f);
                    nb_y[pos] = (yj - yi) * (1.0f / 0.12f);
                    nb_z[pos] = (zj - zi) * (1.0f / 0.12f);
                }
            }
        }
    }
    __syncthreads();
    const int nn = min(nb_cnt, 512);
    const float a0 = A[t], a1 = A[ENC + t], a2 = A[2 * ENC + t];
    float gr = 0.f, gi = 0.f;
    #pragma unroll 4
    for (int m = 0; m < nn; ++m) {
        float pa = fmaf(nb_z[m], a2, fmaf(nb_y[m], a1, nb_x[m] * a0));
        float sv, cv;
        fast_sincos(pa, sv, cv);
        gr += cv; gi += sv;
    }
    float m2 = fmaf(gr, gr, gi * gi);
    #pragma unroll
    for (int off = 32; off > 0; off >>= 1) m2 += __shfl_down(m2, off);
    const int wid = t >> 6;
    if (lane == 0) red[wid] = m2;
    __syncthreads();
    if (t == 0) {
        float tot = 0.f;
        for (int w = 0; w < NTHREAD / 64; ++w) tot += red[w];
        red[7] = tot;
    }
    __syncthreads();
    const float scale = sqrtf(384.0f / red[7]);
    const float re = gr * scale, im = gi * scale;
    if (out_mode == 0) out[i * ENC + t] = re;
    else ((float2*)out)[i * ENC + t] = make_float2(re, im);
}

extern "C" void kernel_launch(void* const* d_in, const int* in_sizes, int n_in,
                              void* d_out, int out_size, void* d_ws, size_t ws_size,
                              hipStream_t stream) {
    const float* pts = (const float*)d_in[0];
    const float* A   = (const float*)d_in[1];
    float* out = (float*)d_out;
    const int out_mode = (out_size >= 2 * N_PTS * ENC) ? 1 : 0;

    if (ws_size >= WS_FULL_B) {
        int*            cell_start = (int*)d_ws + OFF_CSTART_I;
        float4*         spts       = (float4*)((char*)d_ws + OFF_SPTS_B);
        unsigned short* csT        = (unsigned short*)((char*)d_ws + OFF_CST_B);

        k_prep<<<1, 1024, 0, stream>>>(pts, cell_start, spts);
        k_encode<<<ENC, NTHREAD, 0, stream>>>(spts, A, csT);
        k_main<<<2 * NCELLS, NTHREAD, 0, stream>>>(spts, cell_start, csT, A, out, out_mode);
    } else {
        vecKM_allpairs<<<N_PTS, NTHREAD, 0, stream>>>(pts, A, out, out_mode);
    }
}

// Round 10
// 117.326 us; speedup vs baseline: 1.4911x; 1.4911x over previous
//
#include <hip/hip_runtime.h>
#include <hip/hip_fp16.h>
#include <math.h>

#define N_PTS   8192
#define ENC     384
#define NTHREAD 384
#define NCELL1  8
#define NCELLS  512
#define RADIUS  0.12f
#define MAXCH   256          // max 8-candidate chunks per cell (avg ~64)
#define MB_STRIDE 258        // mbb row stride: 258*2=516 B -> banks spread (not 512)

typedef _Float16 f16x8 __attribute__((ext_vector_type(8)));
typedef float    f32x4 __attribute__((ext_vector_type(4)));

__device__ __forceinline__ void fast_sincos(float x, float& s, float& c) {
    // gfx950 v_sin/v_cos take REVOLUTIONS. rev err <= |x|*2^-24 — negligible here.
    float rev = x * 0.15915494309189535f;
    rev -= rintf(rev);
    s = __builtin_amdgcn_sinf(rev);
    c = __builtin_amdgcn_cosf(rev);
}

__device__ __forceinline__ int cell_of(float x) {
    int c = (int)(x * 8.0f);
    return min(NCELL1 - 1, max(0, c));
}

__device__ __forceinline__ f16x8 expand_mask(unsigned m) {
    f16x8 r;
    #pragma unroll
    for (int e = 0; e < 8; ++e)
        r[e] = ((m >> e) & 1u) ? (_Float16)1.0f : (_Float16)0.0f;
    return r;
}

// ---------------- ws layout (bytes) ----------------
static const size_t OFF_CSTART_I = 0;                      // 520 ints (513 used)
static const size_t OFF_SPTS_B   = 520 * 4;                // 2080 (16B aligned)
static const size_t OFF_CST_B    = OFF_SPTS_B + (size_t)N_PTS * 16;   // 133152
// csT: [768][8192] f16, SORTED point order. row d<384 = cos_d, row 384+d = sin_d.
static const size_t WS_FULL_B    = OFF_CST_B + (size_t)2 * ENC * N_PTS * 2 + 1024; // ~12.72MB

// ---------------- K1: count + scan + scatter, one block (proven R7-R9) ----------------
__global__ __launch_bounds__(1024) void k_prep(const float* __restrict__ pts,
                                               int* __restrict__ cell_start_g,
                                               float4* __restrict__ spts) {
    __shared__ int cnt[NCELLS];
    __shared__ int sc[NCELLS];
    __shared__ int cur[NCELLS];
    const int t = threadIdx.x;
    if (t < NCELLS) cnt[t] = 0;
    __syncthreads();

    int   cids[8];
    float xs[8], ys[8], zs[8];
    #pragma unroll
    for (int k = 0; k < 8; ++k) {
        int i = t + k * 1024;
        float x = pts[3 * i + 0], y = pts[3 * i + 1], z = pts[3 * i + 2];
        xs[k] = x; ys[k] = y; zs[k] = z;
        int cid = (cell_of(x) << 6) | (cell_of(y) << 3) | cell_of(z);
        cids[k] = cid;
        atomicAdd(&cnt[cid], 1);
    }
    __syncthreads();
    if (t < NCELLS) sc[t] = cnt[t];
    __syncthreads();
    for (int off = 1; off < NCELLS; off <<= 1) {
        int v = 0;
        if (t < NCELLS && t >= off) v = sc[t - off];
        __syncthreads();
        if (t < NCELLS) sc[t] += v;
        __syncthreads();
    }
    if (t < NCELLS) {
        int excl = sc[t] - cnt[t];
        cell_start_g[t] = excl;
        cur[t] = excl;
    }
    if (t == 0) cell_start_g[NCELLS] = N_PTS;
    __syncthreads();
    #pragma unroll
    for (int k = 0; k < 8; ++k) {
        int i = t + k * 1024;
        int pos = atomicAdd(&cur[cids[k]], 1);
        spts[pos] = make_float4(xs[k], ys[k], zs[k], __int_as_float(i));
    }
}

// ---------------- K2: csT[d][j]=cos, csT[384+d][j]=sin (f16, sorted order) ----------------
__global__ __launch_bounds__(NTHREAD) void k_encode(const float4* __restrict__ spts,
                                                    const float* __restrict__ A,
                                                    unsigned short* __restrict__ csT) {
    const int d = blockIdx.x;          // 0..383
    const int t = threadIdx.x;
    const float a0 = A[d], a1 = A[ENC + d], a2 = A[2 * ENC + d];
    for (int j = t; j < N_PTS; j += NTHREAD) {
        float4 P = spts[j];
        float qx = __fdiv_rn(P.x, RADIUS);
        float qy = __fdiv_rn(P.y, RADIUS);
        float qz = __fdiv_rn(P.z, RADIUS);
        float pa = fmaf(qz, a2, fmaf(qy, a1, qx * a0));
        float s, c;
        fast_sincos(pa, s, c);
        csT[(size_t)d * N_PTS + j]          = __half_as_ushort(__float2half_rn(c));
        csT[(size_t)(ENC + d) * N_PTS + j]  = __half_as_ushort(__float2half_rn(s));
    }
}

// ---------------- K3: per-cell masked GEMM — one mask build, barrier-free stream ----------------
__global__ __launch_bounds__(NTHREAD) void k_main(const float4* __restrict__ spts,
                                                  const int* __restrict__ cell_start,
                                                  const unsigned short* __restrict__ csT,
                                                  const float* __restrict__ A,
                                                  float* __restrict__ out, int out_mode) {
    const int c0   = blockIdx.x;
    const int cell = (c0 & 7) * 64 + (c0 >> 3);   // XCD x-slab swizzle
    const int t    = threadIdx.x;
    const int lane = t & 63;
    const int wg   = t >> 6;       // 0..5 : wave owns dims [64wg, 64wg+64)
    const int l15  = lane & 15;
    const int kq   = lane >> 4;    // 0..3

    __shared__ int run_lo9[9], run_hi9[9], run_nch[9], run_base9[9];
    __shared__ int s_nch_sh;
    __shared__ int meta_l[MAXCH];
    __shared__ unsigned char mbb[16 * MB_STRIDE * 2];   // [l15][chunk] u16: lo8=tile0, hi8=tile1
    __shared__ float4 own_l[32];
    __shared__ float  normw[6][16];
    __shared__ float  scale_l[16];

    const int o_lo = cell_start[cell];
    const int o_hi = cell_start[cell + 1];
    const int n_own = o_hi - o_lo;
    if (n_own <= 0) return;

    const int cx = cell >> 6, cy = (cell >> 3) & 7, cz = cell & 7;
    const int zlo = max(cz - 1, 0), zhi = min(cz + 1, 7);

    // ---- chunk list: 9 z-runs -> 8-aligned 8-candidate chunks ----
    if (t < 9) {
        int dx = t / 3 - 1, dy = t % 3 - 1;
        int cxx = cx + dx, cyy = cy + dy;
        int lo = 0, hi = 0;
        if (cxx >= 0 && cxx <= 7 && cyy >= 0 && cyy <= 7) {
            int basec = (cxx * 8 + cyy) * 8;
            lo = cell_start[basec + zlo];
            hi = cell_start[basec + zhi + 1];
        }
        run_lo9[t] = lo; run_hi9[t] = hi;
        run_nch[t] = (hi > lo) ? ((hi - (lo & ~7) + 7) >> 3) : 0;
    }
    __syncthreads();
    if (t == 0) {
        int b = 0;
        #pragma unroll
        for (int r = 0; r < 9; ++r) { run_base9[r] = b; b += run_nch[r]; }
        int p = min((b + 3) & ~3, MAXCH);
        for (int cpad = min(b, MAXCH); cpad < p; ++cpad) meta_l[cpad] = 0; // jA=0,vlo=vhi=0
        s_nch_sh = p;
    }
    __syncthreads();
    if (t < 9) {
        int lo = run_lo9[t], hi = run_hi9[t];
        int bb = run_base9[t], n = run_nch[t];
        int jb = lo & ~7;
        for (int k = 0; k < n; ++k) {
            int cc = bb + k;
            if (cc < MAXCH) {
                int jA  = jb + (k << 3);
                int vlo = max(lo - jA, 0);
                int vhi = min(hi - jA, 8);
                meta_l[cc] = jA | (vlo << 16) | (vhi << 20);
            }
        }
    }
    __syncthreads();
    const int s_nch = s_nch_sh;
    const int nst = s_nch >> 2;

    const double R2 = (double)0.12 * (double)0.12;
    const float R2_LO = 0.0144f - 1e-6f;
    const float R2_HI = 0.0144f + 1e-6f;

    for (int base = 0; base < n_own; base += 32) {
        if (t < 32) {
            int idx = o_lo + base + t;
            own_l[t] = (idx < o_hi) ? spts[idx] : make_float4(1e9f, 1e9f, 1e9f, 0.f);
        }
        __syncthreads();
        const int n_slots = min(n_own - base, 32);
        const bool two = n_slots > 16;

        // ---- mask build: ALL threads, ONE pass (classification == R5-R9) ----
        for (int idx = t; idx < (s_nch << 5); idx += NTHREAD) {
            int cc = idx >> 5, slot = idx & 31;
            unsigned int m = 0;
            if (slot < n_slots) {
                int meta = meta_l[cc];
                int jA  = meta & 0xFFFF;
                int vlo = (meta >> 16) & 15, vhi = (meta >> 20) & 15;
                float4 Pi = own_l[slot];
                for (int e = vlo; e < vhi; ++e) {
                    float4 Pj = spts[jA + e];
                    float fdx = Pj.x - Pi.x, fdy = Pj.y - Pi.y, fdz = Pj.z - Pi.z;
                    float d2f = fmaf(fdx, fdx, fmaf(fdy, fdy, fdz * fdz));
                    bool isnb = false;
                    if (d2f < R2_LO) {
                        isnb = true;
                    } else if (d2f <= R2_HI) {
                        double ddx = (double)Pj.x - (double)Pi.x;
                        double ddy = (double)Pj.y - (double)Pi.y;
                        double ddz = (double)Pj.z - (double)Pi.z;
                        isnb = (ddx * ddx + ddy * ddy + ddz * ddz) < R2;
                    }
                    if (isnb) m |= 1u << e;
                }
            }
            mbb[((slot & 15) * MB_STRIDE + cc) * 2 + (slot >> 4)] = (unsigned char)m;
        }
        __syncthreads();

        // ---- stream: 6 waves independent, NO barriers ----
        f32x4 z; z[0] = 0.f; z[1] = 0.f; z[2] = 0.f; z[3] = 0.f;
        f32x4 aC0[4] = {z, z, z, z}, aS0[4] = {z, z, z, z};
        f32x4 aC1[4] = {z, z, z, z}, aS1[4] = {z, z, z, z};
        for (int s = 0; s < nst; ++s) {
            const int cc = (s << 2) + kq;
            const int meta = meta_l[cc];
            const int jA = meta & 0xFFFF;
            unsigned int mw = *(const unsigned short*)&mbb[(l15 * MB_STRIDE + cc) * 2];
            f16x8 af0 = expand_mask(mw & 0xFFu);
            f16x8 af1;
            if (two) af1 = expand_mask(mw >> 8);
            const unsigned short* bp = csT + jA;
            #pragma unroll
            for (int e2 = 0; e2 < 4; ++e2) {
                const int d = wg * 64 + e2 * 16 + l15;
                f16x8 bc = *(const f16x8*)(bp + (size_t)d * N_PTS);
                f16x8 bs = *(const f16x8*)(bp + (size_t)(ENC + d) * N_PTS);
                aC0[e2] = __builtin_amdgcn_mfma_f32_16x16x32_f16(af0, bc, aC0[e2], 0, 0, 0);
                aS0[e2] = __builtin_amdgcn_mfma_f32_16x16x32_f16(af0, bs, aS0[e2], 0, 0, 0);
                if (two) {
                    aC1[e2] = __builtin_amdgcn_mfma_f32_16x16x32_f16(af1, bc, aC1[e2], 0, 0, 0);
                    aS1[e2] = __builtin_amdgcn_mfma_f32_16x16x32_f16(af1, bs, aS1[e2], 0, 0, 0);
                }
            }
        }

        // ---- epilogue (verbatim R8, verified): norm -> rotate -> scale -> store ----
        auto finish = [&](f32x4* aC, f32x4* aS, int tl) {
            __syncthreads();
            const int tstart = o_lo + base + tl * 16;
            float np[4];
            #pragma unroll
            for (int reg = 0; reg < 4; ++reg) {
                float v = 0.f;
                #pragma unroll
                for (int e2 = 0; e2 < 4; ++e2)
                    v += aC[e2][reg] * aC[e2][reg] + aS[e2][reg] * aS[e2][reg];
                #pragma unroll
                for (int w = 1; w <= 8; w <<= 1) v += __shfl_xor(v, w);
                np[reg] = v;
            }
            if (l15 == 0) {
                #pragma unroll
                for (int reg = 0; reg < 4; ++reg) normw[wg][kq * 4 + reg] = np[reg];
            }
            __syncthreads();
            if (t < 16) {
                float tot = normw[0][t] + normw[1][t] + normw[2][t]
                          + normw[3][t] + normw[4][t] + normw[5][t];
                scale_l[t] = sqrtf(384.0f / tot);
            }
            __syncthreads();
            #pragma unroll
            for (int e2 = 0; e2 < 4; ++e2) {
                const int d = wg * 64 + e2 * 16 + l15;
                const float a0 = A[d], a1 = A[ENC + d], a2 = A[2 * ENC + d];
                #pragma unroll
                for (int reg = 0; reg < 4; ++reg) {
                    const int i = kq * 4 + reg;   // C/D row = (lane>>4)*4 + reg [m89, R8]
                    if (tstart + i < o_hi) {
                        float4 Po = own_l[tl * 16 + i];
                        int o = __float_as_int(Po.w);
                        float qx = __fdiv_rn(Po.x, RADIUS);
                        float qy = __fdiv_rn(Po.y, RADIUS);
                        float qz = __fdiv_rn(Po.z, RADIUS);
                        float pa = fmaf(qz, a2, fmaf(qy, a1, qx * a0));
                        float sv, cv;
                        fast_sincos(pa, sv, cv);
                        float Gr = aC[e2][reg], Gi = aS[e2][reg];
                        float sc = scale_l[i];
                        float re = (Gr * cv + Gi * sv) * sc;
                        float im = (Gi * cv - Gr * sv) * sc;
                        if (out_mode == 0) {
                            out[(size_t)o * ENC + d] = re;
                        } else {
                            reinterpret_cast<float2*>(out)[(size_t)o * ENC + d] =
                                make_float2(re, im);
                        }
                    }
                }
            }
        };
        finish(aC0, aS0, 0);
        if (two) finish(aC1, aS1, 1);
        __syncthreads();   // protect own_l/mbb before next base group
    }
}

// ---------------- last-resort all-pairs (ws too small; effectively dead) ----------------
__global__ __launch_bounds__(NTHREAD) void vecKM_allpairs(const float* __restrict__ pts,
                                                          const float* __restrict__ A,
                                                          float* __restrict__ out, int out_mode) {
    const int i = blockIdx.x;
    const int t = threadIdx.x;
    __shared__ float nb_x[512], nb_y[512], nb_z[512];
    __shared__ int nb_cnt;
    __shared__ float red[8];
    if (t == 0) nb_cnt = 0;
    __syncthreads();
    const float xi = pts[3 * i + 0], yi = pts[3 * i + 1], zi = pts[3 * i + 2];
    const double dxi = xi, dyi = yi, dzi = zi;
    const double R2 = (double)0.12 * (double)0.12;
    const float R2_LO = 0.0144f - 1e-6f, R2_HI = 0.0144f + 1e-6f;
    const int lane = t & 63;
    for (int jb = 0; jb < N_PTS; jb += NTHREAD) {
        const int j = jb + t;
        bool isnb = false;
        float xj = 0.f, yj = 0.f, zj = 0.f;
        if (j < N_PTS) {
            xj = pts[3 * j + 0]; yj = pts[3 * j + 1]; zj = pts[3 * j + 2];
            float fdx = xj - xi, fdy = yj - yi, fdz = zj - zi;
            float d2f = fmaf(fdx, fdx, fmaf(fdy, fdy, fdz * fdz));
            if (d2f < R2_LO) isnb = true;
            else if (d2f <= R2_HI) {
                double dx = (double)xj - dxi, dy = (double)yj - dyi, dz = (double)zj - dzi;
                isnb = (dx * dx + dy * dy + dz * dz) < R2;
            }
        }
        unsigned long long mask = __ballot(isnb);
        if (mask) {
            int leader = __ffsll((long long)mask) - 1;
            int basep = 0;
            if (lane == leader) basep = atomicAdd(&nb_cnt, __popcll(mask));
            basep = __shfl(basep, leader);
            if (isnb) {
                int pos = basep + __popcll(mask & ((1ull << lane) - 1ull));
                if (pos < 512) {
                    nb_x[pos] = (xj - xi) * (1.0f / 0.12f);
                    nb_y[pos] = (yj - yi) * (1.0f / 0.12f);
                    nb_z[pos] = (zj - zi) * (1.0f / 0.12f);
                }
            }
        }
    }
    __syncthreads();
    const int nn = min(nb_cnt, 512);
    const float a0 = A[t], a1 = A[ENC + t], a2 = A[2 * ENC + t];
    float gr = 0.f, gi = 0.f;
    #pragma unroll 4
    for (int m = 0; m < nn; ++m) {
        float pa = fmaf(nb_z[m], a2, fmaf(nb_y[m], a1, nb_x[m] * a0));
        float sv, cv;
        fast_sincos(pa, sv, cv);
        gr += cv; gi += sv;
    }
    float m2 = fmaf(gr, gr, gi * gi);
    #pragma unroll
    for (int off = 32; off > 0; off >>= 1) m2 += __shfl_down(m2, off);
    const int wid = t >> 6;
    if (lane == 0) red[wid] = m2;
    __syncthreads();
    if (t == 0) {
        float tot = 0.f;
        for (int w = 0; w < NTHREAD / 64; ++w) tot += red[w];
        red[7] = tot;
    }
    __syncthreads();
    const float scale = sqrtf(384.0f / red[7]);
    const float re = gr * scale, im = gi * scale;
    if (out_mode == 0) out[i * ENC + t] = re;
    else ((float2*)out)[i * ENC + t] = make_float2(re, im);
}

extern "C" void kernel_launch(void* const* d_in, const int* in_sizes, int n_in,
                              void* d_out, int out_size, void* d_ws, size_t ws_size,
                              hipStream_t stream) {
    const float* pts = (const float*)d_in[0];
    const float* A   = (const float*)d_in[1];
    float* out = (float*)d_out;
    const int out_mode = (out_size >= 2 * N_PTS * ENC) ? 1 : 0;

    if (ws_size >= WS_FULL_B) {
        int*            cell_start = (int*)d_ws + OFF_CSTART_I;
        float4*         spts       = (float4*)((char*)d_ws + OFF_SPTS_B);
        unsigned short* csT        = (unsigned short*)((char*)d_ws + OFF_CST_B);

        k_prep<<<1, 1024, 0, stream>>>(pts, cell_start, spts);
        k_encode<<<ENC, NTHREAD, 0, stream>>>(spts, A, csT);
        k_main<<<NCELLS, NTHREAD, 0, stream>>>(spts, cell_start, csT, A, out, out_mode);
    } else {
        vecKM_allpairs<<<N_PTS, NTHREAD, 0, stream>>>(pts, A, out, out_mode);
    }
}

// Round 11
// 90.627 us; speedup vs baseline: 1.9304x; 1.2946x over previous
//
#include <hip/hip_runtime.h>
#include <hip/hip_fp16.h>
#include <math.h>

#define N_PTS   8192
#define ENC     384
#define NTHREAD 384
#define NCELL1  8
#define NCELLS  512
#define RADIUS  0.12f
#define MAXNB   512
#define MAXG    256          // per-group cap (2 groups)

__device__ __forceinline__ void fast_sincos(float x, float& s, float& c) {
    // gfx950 v_sin/v_cos take REVOLUTIONS. rev err <= |x|*2^-24 — negligible here.
    float rev = x * 0.15915494309189535f;
    rev -= rintf(rev);
    s = __builtin_amdgcn_sinf(rev);
    c = __builtin_amdgcn_cosf(rev);
}

__device__ __forceinline__ int cell_of(float x) {
    int c = (int)(x * 8.0f);
    return min(NCELL1 - 1, max(0, c));
}

// ---------------- ws layout (bytes) ----------------
static const size_t OFF_CSTART_I = 0;                      // 520 ints (513 used)
static const size_t OFF_SPTS_B   = 520 * 4;                // 2080 (16B aligned)
static const size_t OFF_CS_B     = OFF_SPTS_B + (size_t)N_PTS * 16;   // 133152
// cs: (N_PTS+1) rows x 384 half2 (c,s), SORTED point order; row 8192 = zero dummy
static const size_t WS_FULL_B    = OFF_CS_B + (size_t)(N_PTS + 1) * ENC * 4 + 1024;

// ---------------- K1: count + scan + scatter, one block (proven R7-R10) ----------------
__global__ __launch_bounds__(1024) void k_prep(const float* __restrict__ pts,
                                               int* __restrict__ cell_start_g,
                                               float4* __restrict__ spts) {
    __shared__ int cnt[NCELLS];
    __shared__ int sc[NCELLS];
    __shared__ int cur[NCELLS];
    const int t = threadIdx.x;
    if (t < NCELLS) cnt[t] = 0;
    __syncthreads();

    int   cids[8];
    float xs[8], ys[8], zs[8];
    #pragma unroll
    for (int k = 0; k < 8; ++k) {
        int i = t + k * 1024;
        float x = pts[3 * i + 0], y = pts[3 * i + 1], z = pts[3 * i + 2];
        xs[k] = x; ys[k] = y; zs[k] = z;
        int cid = (cell_of(x) << 6) | (cell_of(y) << 3) | cell_of(z);
        cids[k] = cid;
        atomicAdd(&cnt[cid], 1);
    }
    __syncthreads();
    if (t < NCELLS) sc[t] = cnt[t];
    __syncthreads();
    for (int off = 1; off < NCELLS; off <<= 1) {
        int v = 0;
        if (t < NCELLS && t >= off) v = sc[t - off];
        __syncthreads();
        if (t < NCELLS) sc[t] += v;
        __syncthreads();
    }
    if (t < NCELLS) {
        int excl = sc[t] - cnt[t];
        cell_start_g[t] = excl;
        cur[t] = excl;
    }
    if (t == 0) cell_start_g[NCELLS] = N_PTS;
    __syncthreads();
    #pragma unroll
    for (int k = 0; k < 8; ++k) {
        int i = t + k * 1024;
        int pos = atomicAdd(&cur[cids[k]], 1);
        spts[pos] = make_float4(xs[k], ys[k], zs[k], __int_as_float(i));
    }
}

// ---------------- K2: cs[pos][d] = (cos,sin) fp16, SORTED order; 8 pts/block ----------------
__global__ __launch_bounds__(NTHREAD) void k_encode(const float4* __restrict__ spts,
                                                    const float* __restrict__ A,
                                                    __half2* __restrict__ cs) {
    const int t  = threadIdx.x;
    const int p0 = blockIdx.x * 8;
    const float a0 = A[t], a1 = A[ENC + t], a2 = A[2 * ENC + t];
    #pragma unroll
    for (int k = 0; k < 8; ++k) {
        int p = p0 + k;
        if (p > N_PTS) break;
        if (p == N_PTS) {                 // dummy zero row for padded gathers
            cs[(size_t)p * ENC + t] = __floats2half2_rn(0.f, 0.f);
            break;
        }
        float4 P = spts[p];
        float qx = __fdiv_rn(P.x, RADIUS);
        float qy = __fdiv_rn(P.y, RADIUS);
        float qz = __fdiv_rn(P.z, RADIUS);
        float pa = fmaf(qz, a2, fmaf(qy, a1, qx * a0));
        float s, c;
        fast_sincos(pa, s, c);
        cs[(size_t)p * ENC + t] = __floats2half2_rn(c, s);
    }
}

// ---------------- K3: main — R6 structure, 2 dims/thread uint2 gather ----------------
__global__ __launch_bounds__(NTHREAD) void k_main(const float4* __restrict__ spts,
                                                  const int* __restrict__ cell_start,
                                                  const uint2* __restrict__ cs2,  // row = 192 uint2
                                                  float* __restrict__ out, int out_mode) {
    // chunked XCD swizzle: consecutive sorted points share an XCD's L2 window
    const int p = (blockIdx.x % 8) * (N_PTS / 8) + blockIdx.x / 8;
    const int t = threadIdx.x, lane = t & 63, wv = t >> 6;
    const int g = (wv >= 3);                 // neighbor group 0/1
    const int q = (wv - 3 * g) * 64 + lane;  // dim-pair 0..191 (dims 2q, 2q+1)

    __shared__ __align__(16) unsigned short nb_idx_g2[2][MAXG];
    __shared__ int    nb_cnt;
    __shared__ float4 comb[192];
    __shared__ float  red[3];
    __shared__ float  scale_s;
    if (t == 0) nb_cnt = 0;
    __syncthreads();

    const float4 Pi = spts[p];
    const float xi = Pi.x, yi = Pi.y, zi = Pi.z;
    const double dxi = (double)xi, dyi = (double)yi, dzi = (double)zi;
    const double R2 = (double)0.12 * (double)0.12;
    const float R2_LO = 0.0144f - 1e-6f;
    const float R2_HI = 0.0144f + 1e-6f;

    const int cx = cell_of(xi), cy = cell_of(yi), cz = cell_of(zi);
    const int zlo = max(cz - 1, 0), zhi = min(cz + 1, NCELL1 - 1);

    // ---- Phase 1: candidate scan over 3x3 cell columns (classification == R5-R10) ----
    for (int r = wv; r < 9; r += 6) {
        int cxx = cx + (r / 3) - 1;
        int cyy = cy + (r % 3) - 1;
        if (cxx < 0 || cxx >= NCELL1 || cyy < 0 || cyy >= NCELL1) continue;
        int base_c = (cxx * NCELL1 + cyy) * NCELL1;
        int lo = cell_start[base_c + zlo];
        int hi = cell_start[base_c + zhi + 1];
        for (int jb = lo; jb < hi; jb += 64) {
            int j = jb + lane;
            bool isnb = false;
            if (j < hi) {
                float4 Pj = spts[j];
                float fdx = Pj.x - xi, fdy = Pj.y - yi, fdz = Pj.z - zi;
                float d2f = fmaf(fdx, fdx, fmaf(fdy, fdy, fdz * fdz));
                if (d2f < R2_LO) {
                    isnb = true;
                } else if (d2f <= R2_HI) {
                    double ddx = (double)Pj.x - dxi, ddy = (double)Pj.y - dyi, ddz = (double)Pj.z - dzi;
                    isnb = (ddx * ddx + ddy * ddy + ddz * ddz) < R2;
                }
            }
            unsigned long long mask = __ballot(isnb);
            if (mask) {
                int leader = __ffsll((long long)mask) - 1;
                int basep = 0;
                if (lane == leader) basep = atomicAdd(&nb_cnt, __popcll(mask));
                basep = __shfl(basep, leader);
                if (isnb) {
                    int pos = basep + __popcll(mask & ((1ull << lane) - 1ull));
                    if (pos < MAXNB) nb_idx_g2[pos & 1][pos >> 1] = (unsigned short)j;
                }
            }
        }
    }
    __syncthreads();
    const int nn = min(nb_cnt, MAXNB);
    if (t < 32) {                            // pad each group to x8 with dummy row
        int gg = t >> 4, k = t & 15;
        int ng = (nn + 1 - gg) >> 1;
        int P8 = min((ng + 7) & ~7, MAXG);
        for (int s = ng + k; s < P8; s += 16) nb_idx_g2[gg][s] = (unsigned short)N_PTS;
    }
    __syncthreads();
    {
        // ---- Phase 2: group g streams its neighbors; thread covers dims 2q,2q+1 ----
        const int ng = (nn + 1 - g) >> 1;
        const int P8 = min((ng + 7) & ~7, MAXG);
        __half2 ac_lo = __floats2half2_rn(0.f, 0.f);
        __half2 ac_hi = ac_lo;
        const uint2* csq = cs2 + q;
        for (int m = 0; m < P8; m += 8) {
            uint4 iv = *reinterpret_cast<const uint4*>(&nb_idx_g2[g][m]);  // 8 u16 idx
            int j0 = (int)(iv.x & 0xFFFFu), j1 = (int)(iv.x >> 16);
            int j2 = (int)(iv.y & 0xFFFFu), j3 = (int)(iv.y >> 16);
            int j4 = (int)(iv.z & 0xFFFFu), j5 = (int)(iv.z >> 16);
            int j6 = (int)(iv.w & 0xFFFFu), j7 = (int)(iv.w >> 16);
            uint2 v0 = csq[j0 * 192];
            uint2 v1 = csq[j1 * 192];
            uint2 v2 = csq[j2 * 192];
            uint2 v3 = csq[j3 * 192];
            uint2 v4 = csq[j4 * 192];
            uint2 v5 = csq[j5 * 192];
            uint2 v6 = csq[j6 * 192];
            uint2 v7 = csq[j7 * 192];
            #define ACC(V) \
                ac_lo = __hadd2(ac_lo, *reinterpret_cast<const __half2*>(&V.x)); \
                ac_hi = __hadd2(ac_hi, *reinterpret_cast<const __half2*>(&V.y));
            ACC(v0) ACC(v1) ACC(v2) ACC(v3) ACC(v4) ACC(v5) ACC(v6) ACC(v7)
            #undef ACC
        }
        float2 f_lo = __half22float2(ac_lo);   // (sum c_2q,  sum s_2q)
        float2 f_hi = __half22float2(ac_hi);   // (sum c_2q+1, sum s_2q+1)
        if (g == 1) comb[q] = make_float4(f_lo.x, f_lo.y, f_hi.x, f_hi.y);
        __syncthreads();

        float gr0 = f_lo.x, gi0 = f_lo.y, gr1 = f_hi.x, gi1 = f_hi.y;
        if (g == 0) {
            float4 o = comb[q];
            gr0 += o.x; gi0 += o.y; gr1 += o.z; gi1 += o.w;
            // ---- Phase 3a: norm partial (phase-invariant) ----
            float m2 = gr0 * gr0 + gi0 * gi0 + gr1 * gr1 + gi1 * gi1;
            #pragma unroll
            for (int off = 32; off > 0; off >>= 1) m2 += __shfl_down(m2, off);
            if (lane == 0) red[wv] = m2;
        }
        __syncthreads();
        if (t == 0) scale_s = sqrtf(384.0f / (red[0] + red[1] + red[2]));
        __syncthreads();

        if (g == 0) {
            // ---- Phase 3b: rotate by conj(own phase) from table, scale, store ----
            const float sc = scale_s;
            uint2 ov = csq[p * 192];
            float2 o_lo = __half22float2(*reinterpret_cast<const __half2*>(&ov.x));
            float2 o_hi = __half22float2(*reinterpret_cast<const __half2*>(&ov.y));
            float re0 = (gr0 * o_lo.x + gi0 * o_lo.y) * sc;
            float im0 = (gi0 * o_lo.x - gr0 * o_lo.y) * sc;
            float re1 = (gr1 * o_hi.x + gi1 * o_hi.y) * sc;
            float im1 = (gi1 * o_hi.x - gr1 * o_hi.y) * sc;
            const int o = __float_as_int(Pi.w);
            if (out_mode == 0) {
                reinterpret_cast<float2*>(out)[o * 192 + q] = make_float2(re0, re1);
            } else {
                reinterpret_cast<float4*>(out)[o * 192 + q] = make_float4(re0, im0, re1, im1);
            }
        }
    }
}

// ---------------- last-resort all-pairs (ws too small; effectively dead) ----------------
__global__ __launch_bounds__(NTHREAD) void vecKM_allpairs(const float* __restrict__ pts,
                                                          const float* __restrict__ A,
                                                          float* __restrict__ out, int out_mode) {
    const int i = blockIdx.x;
    const int t = threadIdx.x;
    __shared__ float nb_x[512], nb_y[512], nb_z[512];
    __shared__ int nb_cnt;
    __shared__ float red[8];
    if (t == 0) nb_cnt = 0;
    __syncthreads();
    const float xi = pts[3 * i + 0], yi = pts[3 * i + 1], zi = pts[3 * i + 2];
    const double dxi = xi, dyi = yi, dzi = zi;
    const double R2 = (double)0.12 * (double)0.12;
    const float R2_LO = 0.0144f - 1e-6f, R2_HI = 0.0144f + 1e-6f;
    const int lane = t & 63;
    for (int jb = 0; jb < N_PTS; jb += NTHREAD) {
        const int j = jb + t;
        bool isnb = false;
        float xj = 0.f, yj = 0.f, zj = 0.f;
        if (j < N_PTS) {
            xj = pts[3 * j + 0]; yj = pts[3 * j + 1]; zj = pts[3 * j + 2];
            float fdx = xj - xi, fdy = yj - yi, fdz = zj - zi;
            float d2f = fmaf(fdx, fdx, fmaf(fdy, fdy, fdz * fdz));
            if (d2f < R2_LO) isnb = true;
            else if (d2f <= R2_HI) {
                double dx = (double)xj - dxi, dy = (double)yj - dyi, dz = (double)zj - dzi;
                isnb = (dx * dx + dy * dy + dz * dz) < R2;
            }
        }
        unsigned long long mask = __ballot(isnb);
        if (mask) {
            int leader = __ffsll((long long)mask) - 1;
            int basep = 0;
            if (lane == leader) basep = atomicAdd(&nb_cnt, __popcll(mask));
            basep = __shfl(basep, leader);
            if (isnb) {
                int pos = basep + __popcll(mask & ((1ull << lane) - 1ull));
                if (pos < 512) {
                    nb_x[pos] = (xj - xi) * (1.0f / 0.12f);
                    nb_y[pos] = (yj - yi) * (1.0f / 0.12f);
                    nb_z[pos] = (zj - zi) * (1.0f / 0.12f);
                }
            }
        }
    }
    __syncthreads();
    const int nn = min(nb_cnt, 512);
    const float a0 = A[t], a1 = A[ENC + t], a2 = A[2 * ENC + t];
    float gr = 0.f, gi = 0.f;
    #pragma unroll 4
    for (int m = 0; m < nn; ++m) {
        float pa = fmaf(nb_z[m], a2, fmaf(nb_y[m], a1, nb_x[m] * a0));
        float sv, cv;
        fast_sincos(pa, sv, cv);
        gr += cv; gi += sv;
    }
    float m2 = fmaf(gr, gr, gi * gi);
    #pragma unroll
    for (int off = 32; off > 0; off >>= 1) m2 += __shfl_down(m2, off);
    const int wid = t >> 6;
    if (lane == 0) red[wid] = m2;
    __syncthreads();
    if (t == 0) {
        float tot = 0.f;
        for (int w = 0; w < NTHREAD / 64; ++w) tot += red[w];
        red[7] = tot;
    }
    __syncthreads();
    const float scale = sqrtf(384.0f / red[7]);
    const float re = gr * scale, im = gi * scale;
    if (out_mode == 0) out[i * ENC + t] = re;
    else ((float2*)out)[i * ENC + t] = make_float2(re, im);
}

extern "C" void kernel_launch(void* const* d_in, const int* in_sizes, int n_in,
                              void* d_out, int out_size, void* d_ws, size_t ws_size,
                              hipStream_t stream) {
    const float* pts = (const float*)d_in[0];
    const float* A   = (const float*)d_in[1];
    float* out = (float*)d_out;
    const int out_mode = (out_size >= 2 * N_PTS * ENC) ? 1 : 0;

    if (ws_size >= WS_FULL_B) {
        int*     cell_start = (int*)d_ws + OFF_CSTART_I;
        float4*  spts       = (float4*)((char*)d_ws + OFF_SPTS_B);
        __half2* cs         = (__half2*)((char*)d_ws + OFF_CS_B);

        k_prep<<<1, 1024, 0, stream>>>(pts, cell_start, spts);
        k_encode<<<(N_PTS / 8) + 1, NTHREAD, 0, stream>>>(spts, A, cs);
        k_main<<<N_PTS, NTHREAD, 0, stream>>>(spts, cell_start,
                                              (const uint2*)cs, out, out_mode);
    } else {
        vecKM_allpairs<<<N_PTS, NTHREAD, 0, stream>>>(pts, A, out, out_mode);
    }
}

// Round 12
// 70.599 us; speedup vs baseline: 2.4781x; 1.2837x over previous
//
#include <hip/hip_runtime.h>
#include <hip/hip_fp16.h>
#include <math.h>

#define N_PTS   8192
#define ENC     384
#define NTHREAD 384
#define NCELL1  8
#define NCELLS  512
#define RADIUS  0.12f
#define MAXSUB  12          // subtiles per cell (covers 48 pts single-pass; loops beyond)
#define MAXU    368         // union-list cap (avg ~95, +28 sigma unreachable)

__device__ __forceinline__ void fast_sincos(float x, float& s, float& c) {
    // gfx950 v_sin/v_cos take REVOLUTIONS. rev err <= |x|*2^-24 — negligible here.
    float rev = x * 0.15915494309189535f;
    rev -= rintf(rev);
    s = __builtin_amdgcn_sinf(rev);
    c = __builtin_amdgcn_cosf(rev);
}

__device__ __forceinline__ int cell_of(float x) {
    int c = (int)(x * 8.0f);
    return min(NCELL1 - 1, max(0, c));
}

static __device__ __forceinline__ unsigned h2u(__half2 h) { union { __half2 h; unsigned u; } x; x.h = h; return x.u; }
static __device__ __forceinline__ __half2 u2h(unsigned u) { union { unsigned u; __half2 h; } x; x.u = u; return x.h; }

// ---------------- ws layout (bytes) ----------------
static const size_t OFF_CSTART_I = 0;                      // 520 ints (513 used)
static const size_t OFF_SPTS_B   = 520 * 4;                // 2080 (16B aligned)
static const size_t OFF_CS_B     = OFF_SPTS_B + (size_t)N_PTS * 16;   // 133152
// cs: (N_PTS+1) rows x 384 half2 (c,s), SORTED order; row 8192 = zero dummy
static const size_t WS_FULL_B    = OFF_CS_B + (size_t)(N_PTS + 1) * ENC * 4 + 1024;

// ---------------- K1: count + scan + scatter, one block (proven R7-R11) ----------------
__global__ __launch_bounds__(1024) void k_prep(const float* __restrict__ pts,
                                               int* __restrict__ cell_start_g,
                                               float4* __restrict__ spts) {
    __shared__ int cnt[NCELLS];
    __shared__ int sc[NCELLS];
    __shared__ int cur[NCELLS];
    const int t = threadIdx.x;
    if (t < NCELLS) cnt[t] = 0;
    __syncthreads();

    int   cids[8];
    float xs[8], ys[8], zs[8];
    #pragma unroll
    for (int k = 0; k < 8; ++k) {
        int i = t + k * 1024;
        float x = pts[3 * i + 0], y = pts[3 * i + 1], z = pts[3 * i + 2];
        xs[k] = x; ys[k] = y; zs[k] = z;
        int cid = (cell_of(x) << 6) | (cell_of(y) << 3) | cell_of(z);
        cids[k] = cid;
        atomicAdd(&cnt[cid], 1);
    }
    __syncthreads();
    if (t < NCELLS) sc[t] = cnt[t];
    __syncthreads();
    for (int off = 1; off < NCELLS; off <<= 1) {
        int v = 0;
        if (t < NCELLS && t >= off) v = sc[t - off];
        __syncthreads();
        if (t < NCELLS) sc[t] += v;
        __syncthreads();
    }
    if (t < NCELLS) {
        int excl = sc[t] - cnt[t];
        cell_start_g[t] = excl;
        cur[t] = excl;
    }
    if (t == 0) cell_start_g[NCELLS] = N_PTS;
    __syncthreads();
    #pragma unroll
    for (int k = 0; k < 8; ++k) {
        int i = t + k * 1024;
        int pos = atomicAdd(&cur[cids[k]], 1);
        spts[pos] = make_float4(xs[k], ys[k], zs[k], __int_as_float(i));
    }
}

// ---------------- K2: cs[pos][d] = (cos,sin) fp16, SORTED order; 8 pts/block ----------------
__global__ __launch_bounds__(NTHREAD) void k_encode(const float4* __restrict__ spts,
                                                    const float* __restrict__ A,
                                                    __half2* __restrict__ cs) {
    const int t  = threadIdx.x;
    const int p0 = blockIdx.x * 8;
    const float a0 = A[t], a1 = A[ENC + t], a2 = A[2 * ENC + t];
    #pragma unroll
    for (int k = 0; k < 8; ++k) {
        int p = p0 + k;
        if (p > N_PTS) break;
        if (p == N_PTS) {                 // dummy zero row for padded gathers
            cs[(size_t)p * ENC + t] = __floats2half2_rn(0.f, 0.f);
            break;
        }
        float4 P = spts[p];
        float qx = __fdiv_rn(P.x, RADIUS);
        float qy = __fdiv_rn(P.y, RADIUS);
        float qz = __fdiv_rn(P.z, RADIUS);
        float pa = fmaf(qz, a2, fmaf(qy, a1, qx * a0));
        float s, c;
        fast_sincos(pa, s, c);
        cs[(size_t)p * ENC + t] = __floats2half2_rn(c, s);
    }
}

// ---------------- K3: main — 4 points/block, shared union-row gather ----------------
// grid = 8 XCDs x 64 cells/slab x MAXSUB subtiles. Subtile s handles point-chunks
// s, s+MAXSUB, ... of its cell (chunks of 4 consecutive sorted points).
__global__ __launch_bounds__(NTHREAD) void k_main(const float4* __restrict__ spts,
                                                  const int* __restrict__ cell_start,
                                                  const uint4* __restrict__ cs4,  // row = 96 uint4
                                                  float* __restrict__ out, int out_mode) {
    const int b    = blockIdx.x;
    const int cell = (b & 7) * 64 + ((b >> 3) & 63);   // XCD x-slab swizzle
    const int s    = b >> 9;                            // subtile 0..MAXSUB-1
    const int t = threadIdx.x, lane = t & 63, wv = t >> 6;
    const int g = t / 96, q = t - g * 96;               // group 0..3; dims 4q..4q+3

    __shared__ int    run_lo[9], run_hi[9];
    __shared__ float4 own_l[4];
    __shared__ int    ne;
    __shared__ __align__(16) unsigned int ent_g[4][96];   // entry = idx | mask<<16
    __shared__ uint4  comb_a[96][4];
    __shared__ uint4  comb_b[96][4];
    __shared__ float  red2[96][4];
    __shared__ float  scale_l[4];

    const int o_lo = cell_start[cell];
    const int o_hi = cell_start[cell + 1];
    const int n_own = o_hi - o_lo;
    if (n_own <= 0 || 4 * s >= n_own) return;

    // cell-level window: 9 z-runs (invariant across chunks)
    const int cx = cell >> 6, cy = (cell >> 3) & 7, cz = cell & 7;
    if (t < 9) {
        int dx = t / 3 - 1, dy = t % 3 - 1;
        int cxx = cx + dx, cyy = cy + dy;
        int lo = 0, hi = 0;
        if (cxx >= 0 && cxx <= 7 && cyy >= 0 && cyy <= 7) {
            int basec = (cxx * 8 + cyy) * 8;
            int zlo = max(cz - 1, 0), zhi = min(cz + 1, 7);
            lo = cell_start[basec + zlo];
            hi = cell_start[basec + zhi + 1];
        }
        run_lo[t] = lo; run_hi[t] = hi;
    }

    const double R2 = (double)0.12 * (double)0.12;
    const float R2_LO = 0.0144f - 1e-6f;
    const float R2_HI = 0.0144f + 1e-6f;
    const uint4* csq = cs4 + q;

    for (int chunk = s; 4 * chunk < n_own; chunk += MAXSUB) {
        const int pbase = o_lo + 4 * chunk;
        const int np = min(4, o_hi - pbase);

        __syncthreads();                    // prev chunk readers done (also covers run_*)
        if (t == 0) ne = 0;
        if (t < 4) {
            int idx = pbase + t;
            own_l[t] = (idx < o_hi) ? spts[idx] : make_float4(1e9f, 1e9f, 1e9f, 0.f);
        }
        __syncthreads();
        const float4 O0 = own_l[0], O1 = own_l[1], O2 = own_l[2], O3 = own_l[3];

        // ---- Phase 1: union scan, 4-bit membership mask (classification == R5-R11) ----
        for (int r = wv; r < 9; r += 6) {
            const int lo = run_lo[r], hi = run_hi[r];
            for (int jb = lo; jb < hi; jb += 64) {
                int j = jb + lane;
                unsigned mk = 0;
                if (j < hi) {
                    float4 Pj = spts[j];
                    #define TEST(O, BIT) { \
                        float fdx = Pj.x - O.x, fdy = Pj.y - O.y, fdz = Pj.z - O.z; \
                        float d2f = fmaf(fdx, fdx, fmaf(fdy, fdy, fdz * fdz)); \
                        if (d2f < R2_LO) mk |= (BIT); \
                        else if (d2f <= R2_HI) { \
                            double ddx = (double)Pj.x - (double)O.x; \
                            double ddy = (double)Pj.y - (double)O.y; \
                            double ddz = (double)Pj.z - (double)O.z; \
                            if (ddx * ddx + ddy * ddy + ddz * ddz < R2) mk |= (BIT); \
                        } }
                    TEST(O0, 1u) TEST(O1, 2u) TEST(O2, 4u) TEST(O3, 8u)
                    #undef TEST
                }
                unsigned long long mask = __ballot(mk != 0);
                if (mask) {
                    int leader = __ffsll((long long)mask) - 1;
                    int basep = 0;
                    if (lane == leader) basep = atomicAdd(&ne, __popcll(mask));
                    basep = __shfl(basep, leader);
                    if (mk != 0) {
                        int pos = basep + __popcll(mask & ((1ull << lane) - 1ull));
                        if (pos < MAXU) ent_g[pos & 3][pos >> 2] = (unsigned)j | (mk << 16);
                    }
                }
            }
        }
        __syncthreads();
        const int ne_p  = min(ne, MAXU);
        const int total = (ne_p + 15) & ~15;
        if (t < total - ne_p) {
            int pos = ne_p + t;
            ent_g[pos & 3][pos >> 2] = (unsigned)N_PTS;   // dummy row, mask 0
        }
        __syncthreads();
        const int P = total >> 2;            // entries per group (multiple of 4)

        // ---- Phase 2: each row loaded ONCE, mask-fma'd into up to 4 points ----
        __half2 a0[4], a1[4], a2[4], a3[4];
        #pragma unroll
        for (int dd = 0; dd < 4; ++dd) {
            a0[dd] = u2h(0u); a1[dd] = u2h(0u); a2[dd] = u2h(0u); a3[dd] = u2h(0u);
        }
        for (int m = 0; m < P; m += 4) {
            uint4 ev = *(const uint4*)&ent_g[g][m];
            uint4 r0 = csq[(size_t)(ev.x & 0xFFFFu) * 96];
            uint4 r1 = csq[(size_t)(ev.y & 0xFFFFu) * 96];
            uint4 r2 = csq[(size_t)(ev.z & 0xFFFFu) * 96];
            uint4 r3 = csq[(size_t)(ev.w & 0xFFFFu) * 96];
            #define ACC4(R, MK) { \
                unsigned mk_ = (MK); \
                __half2 h0 = u2h((mk_ & 1u) ? 0x3C003C00u : 0u); \
                __half2 h1 = u2h((mk_ & 2u) ? 0x3C003C00u : 0u); \
                __half2 h2 = u2h((mk_ & 4u) ? 0x3C003C00u : 0u); \
                __half2 h3 = u2h((mk_ & 8u) ? 0x3C003C00u : 0u); \
                __half2 rx = u2h(R.x), ry = u2h(R.y), rz = u2h(R.z), rw = u2h(R.w); \
                a0[0] = __hfma2(rx, h0, a0[0]); a0[1] = __hfma2(ry, h0, a0[1]); \
                a0[2] = __hfma2(rz, h0, a0[2]); a0[3] = __hfma2(rw, h0, a0[3]); \
                a1[0] = __hfma2(rx, h1, a1[0]); a1[1] = __hfma2(ry, h1, a1[1]); \
                a1[2] = __hfma2(rz, h1, a1[2]); a1[3] = __hfma2(rw, h1, a1[3]); \
                a2[0] = __hfma2(rx, h2, a2[0]); a2[1] = __hfma2(ry, h2, a2[1]); \
                a2[2] = __hfma2(rz, h2, a2[2]); a2[3] = __hfma2(rw, h2, a2[3]); \
                a3[0] = __hfma2(rx, h3, a3[0]); a3[1] = __hfma2(ry, h3, a3[1]); \
                a3[2] = __hfma2(rz, h3, a3[2]); a3[3] = __hfma2(rw, h3, a3[3]); }
            ACC4(r0, ev.x >> 16) ACC4(r1, ev.y >> 16) ACC4(r2, ev.z >> 16) ACC4(r3, ev.w >> 16)
            #undef ACC4
        }

        // ---- combine 4 groups onto g==0 (R6 tree, 4-point payload) ----
        #define PACK(A) make_uint4(h2u(A[0]), h2u(A[1]), h2u(A[2]), h2u(A[3]))
        #define ADDU(A, V) { A[0] = __hadd2(A[0], u2h(V.x)); A[1] = __hadd2(A[1], u2h(V.y)); \
                             A[2] = __hadd2(A[2], u2h(V.z)); A[3] = __hadd2(A[3], u2h(V.w)); }
        if (g == 1) { comb_a[q][0] = PACK(a0); comb_a[q][1] = PACK(a1); comb_a[q][2] = PACK(a2); comb_a[q][3] = PACK(a3); }
        else if (g == 3) { comb_b[q][0] = PACK(a0); comb_b[q][1] = PACK(a1); comb_b[q][2] = PACK(a2); comb_b[q][3] = PACK(a3); }
        __syncthreads();
        if (g == 0) { uint4 v0 = comb_a[q][0], v1 = comb_a[q][1], v2 = comb_a[q][2], v3 = comb_a[q][3];
                      ADDU(a0, v0) ADDU(a1, v1) ADDU(a2, v2) ADDU(a3, v3) }
        else if (g == 2) { uint4 v0 = comb_b[q][0], v1 = comb_b[q][1], v2 = comb_b[q][2], v3 = comb_b[q][3];
                           ADDU(a0, v0) ADDU(a1, v1) ADDU(a2, v2) ADDU(a3, v3) }
        __syncthreads();
        if (g == 2) { comb_a[q][0] = PACK(a0); comb_a[q][1] = PACK(a1); comb_a[q][2] = PACK(a2); comb_a[q][3] = PACK(a3); }
        __syncthreads();
        if (g == 0) { uint4 v0 = comb_a[q][0], v1 = comb_a[q][1], v2 = comb_a[q][2], v3 = comb_a[q][3];
                      ADDU(a0, v0) ADDU(a1, v1) ADDU(a2, v2) ADDU(a3, v3) }
        #undef PACK
        #undef ADDU

        // ---- Phase 3: norms (phase-invariant) -> scales -> rotate -> store ----
        if (g == 0) {
            #define NORM_P(AC, PP) { float m2 = 0.f; \
                _Pragma("unroll") for (int dd = 0; dd < 4; ++dd) { \
                    float2 f = __half22float2(AC[dd]); \
                    m2 = fmaf(f.x, f.x, fmaf(f.y, f.y, m2)); } \
                red2[q][PP] = m2; }
            NORM_P(a0, 0) NORM_P(a1, 1) NORM_P(a2, 2) NORM_P(a3, 3)
            #undef NORM_P
        }
        __syncthreads();
        if (t < 256) {
            int w = t >> 6, l = t & 63;
            float v = red2[l][w] + (l < 32 ? red2[64 + l][w] : 0.f);
            #pragma unroll
            for (int off = 32; off > 0; off >>= 1) v += __shfl_down(v, off);
            if (l == 0) scale_l[w] = sqrtf(384.0f / v);
        }
        __syncthreads();
        if (g == 0) {
            #define STORE_P(AC, PP) if ((PP) < np) { \
                const float scl = scale_l[PP]; \
                uint4 ov = csq[(size_t)(pbase + (PP)) * 96]; \
                float2 o0 = __half22float2(u2h(ov.x)), o1 = __half22float2(u2h(ov.y)); \
                float2 o2 = __half22float2(u2h(ov.z)), o3 = __half22float2(u2h(ov.w)); \
                float2 g0v = __half22float2(AC[0]), g1v = __half22float2(AC[1]); \
                float2 g2v = __half22float2(AC[2]), g3v = __half22float2(AC[3]); \
                float re0 = (g0v.x * o0.x + g0v.y * o0.y) * scl, im0 = (g0v.y * o0.x - g0v.x * o0.y) * scl; \
                float re1 = (g1v.x * o1.x + g1v.y * o1.y) * scl, im1 = (g1v.y * o1.x - g1v.x * o1.y) * scl; \
                float re2 = (g2v.x * o2.x + g2v.y * o2.y) * scl, im2 = (g2v.y * o2.x - g2v.x * o2.y) * scl; \
                float re3 = (g3v.x * o3.x + g3v.y * o3.y) * scl, im3 = (g3v.y * o3.x - g3v.x * o3.y) * scl; \
                const int o = __float_as_int(own_l[PP].w); \
                if (out_mode == 0) { \
                    ((float4*)out)[(size_t)o * 96 + q] = make_float4(re0, re1, re2, re3); \
                } else { \
                    ((float4*)out)[(size_t)o * 192 + 2 * q + 0] = make_float4(re0, im0, re1, im1); \
                    ((float4*)out)[(size_t)o * 192 + 2 * q + 1] = make_float4(re2, im2, re3, im3); \
                } }
            STORE_P(a0, 0) STORE_P(a1, 1) STORE_P(a2, 2) STORE_P(a3, 3)
            #undef STORE_P
        }
    }
}

// ---------------- last-resort all-pairs (ws too small; effectively dead) ----------------
__global__ __launch_bounds__(NTHREAD) void vecKM_allpairs(const float* __restrict__ pts,
                                                          const float* __restrict__ A,
                                                          float* __restrict__ out, int out_mode) {
    const int i = blockIdx.x;
    const int t = threadIdx.x;
    __shared__ float nb_x[512], nb_y[512], nb_z[512];
    __shared__ int nb_cnt;
    __shared__ float red[8];
    if (t == 0) nb_cnt = 0;
    __syncthreads();
    const float xi = pts[3 * i + 0], yi = pts[3 * i + 1], zi = pts[3 * i + 2];
    const double dxi = xi, dyi = yi, dzi = zi;
    const double R2 = (double)0.12 * (double)0.12;
    const float R2_LO = 0.0144f - 1e-6f, R2_HI = 0.0144f + 1e-6f;
    const int lane = t & 63;
    for (int jb = 0; jb < N_PTS; jb += NTHREAD) {
        const int j = jb + t;
        bool isnb = false;
        float xj = 0.f, yj = 0.f, zj = 0.f;
        if (j < N_PTS) {
            xj = pts[3 * j + 0]; yj = pts[3 * j + 1]; zj = pts[3 * j + 2];
            float fdx = xj - xi, fdy = yj - yi, fdz = zj - zi;
            float d2f = fmaf(fdx, fdx, fmaf(fdy, fdy, fdz * fdz));
            if (d2f < R2_LO) isnb = true;
            else if (d2f <= R2_HI) {
                double dx = (double)xj - dxi, dy = (double)yj - dyi, dz = (double)zj - dzi;
                isnb = (dx * dx + dy * dy + dz * dz) < R2;
            }
        }
        unsigned long long mask = __ballot(isnb);
        if (mask) {
            int leader = __ffsll((long long)mask) - 1;
            int basep = 0;
            if (lane == leader) basep = atomicAdd(&nb_cnt, __popcll(mask));
            basep = __shfl(basep, leader);
            if (isnb) {
                int pos = basep + __popcll(mask & ((1ull << lane) - 1ull));
                if (pos < 512) {
                    nb_x[pos] = (xj - xi) * (1.0f / 0.12f);
                    nb_y[pos] = (yj - yi) * (1.0f / 0.12f);
                    nb_z[pos] = (zj - zi) * (1.0f / 0.12f);
                }
            }
        }
    }
    __syncthreads();
    const int nn = min(nb_cnt, 512);
    const float a0 = A[t], a1 = A[ENC + t], a2 = A[2 * ENC + t];
    float gr = 0.f, gi = 0.f;
    #pragma unroll 4
    for (int m = 0; m < nn; ++m) {
        float pa = fmaf(nb_z[m], a2, fmaf(nb_y[m], a1, nb_x[m] * a0));
        float sv, cv;
        fast_sincos(pa, sv, cv);
        gr += cv; gi += sv;
    }
    float m2 = fmaf(gr, gr, gi * gi);
    #pragma unroll
    for (int off = 32; off > 0; off >>= 1) m2 += __shfl_down(m2, off);
    const int wid = t >> 6;
    if (lane == 0) red[wid] = m2;
    __syncthreads();
    if (t == 0) {
        float tot = 0.f;
        for (int w = 0; w < NTHREAD / 64; ++w) tot += red[w];
        red[7] = tot;
    }
    __syncthreads();
    const float scale = sqrtf(384.0f / red[7]);
    const float re = gr * scale, im = gi * scale;
    if (out_mode == 0) out[i * ENC + t] = re;
    else ((float2*)out)[i * ENC + t] = make_float2(re, im);
}

extern "C" void kernel_launch(void* const* d_in, const int* in_sizes, int n_in,
                              void* d_out, int out_size, void* d_ws, size_t ws_size,
                              hipStream_t stream) {
    const float* pts = (const float*)d_in[0];
    const float* A   = (const float*)d_in[1];
    float* out = (float*)d_out;
    const int out_mode = (out_size >= 2 * N_PTS * ENC) ? 1 : 0;

    if (ws_size >= WS_FULL_B) {
        int*     cell_start = (int*)d_ws + OFF_CSTART_I;
        float4*  spts       = (float4*)((char*)d_ws + OFF_SPTS_B);
        __half2* cs         = (__half2*)((char*)d_ws + OFF_CS_B);

        k_prep<<<1, 1024, 0, stream>>>(pts, cell_start, spts);
        k_encode<<<(N_PTS / 8) + 1, NTHREAD, 0, stream>>>(spts, A, cs);
        k_main<<<8 * 64 * MAXSUB, NTHREAD, 0, stream>>>(spts, cell_start,
                                                        (const uint4*)cs, out, out_mode);
    } else {
        vecKM_allpairs<<<N_PTS, NTHREAD, 0, stream>>>(pts, A, out, out_mode);
    }
}